// Round 1
// baseline (305.474 us; speedup 1.0000x reference)
//
#include <hip/hip_runtime.h>
#include <hip/hip_bf16.h>
#include <cstdint>

typedef unsigned short u16;
typedef __bf16 bf16x8 __attribute__((ext_vector_type(8)));
typedef float floatx4 __attribute__((ext_vector_type(4)));

#define AS1 __attribute__((address_space(1)))
#define AS3 __attribute__((address_space(3)))

// round-to-nearest-even f32 -> bf16 bits (inputs are finite; NaN path not needed)
static __device__ __forceinline__ u16 f2bf(float f) {
    union { float f; unsigned int u; } v; v.f = f;
    unsigned int u = v.u;
    return (u16)((u + 0x7FFFu + ((u >> 16) & 1u)) >> 16);
}

// ---------------------------------------------------------------------------
// Transpose + fp32->bf16 convert: in[R][Ccols] fp32 -> out[Ccols][R] bf16 bits
// R, Ccols multiples of 32. block (32,8), grid (Ccols/32, R/32).
// ---------------------------------------------------------------------------
__global__ __launch_bounds__(256)
void transpose_cvt(const float* __restrict__ in, u16* __restrict__ out,
                   int R, int Ccols)
{
    __shared__ float tile[32][33];
    const int tx = threadIdx.x;   // 0..31
    const int ty = threadIdx.y;   // 0..7
    const int c0 = blockIdx.x * 32;
    const int r0 = blockIdx.y * 32;
#pragma unroll
    for (int i = 0; i < 32; i += 8)
        tile[ty + i][tx] = in[(size_t)(r0 + ty + i) * Ccols + (c0 + tx)];
    __syncthreads();
#pragma unroll
    for (int i = 0; i < 32; i += 8)
        out[(size_t)(c0 + ty + i) * R + (r0 + tx)] = f2bf(tile[tx][ty + i]);
}

// ---------------------------------------------------------------------------
// LayerNorm over last dim (1024) -> bf16. One block (256 thr) per row.
// ---------------------------------------------------------------------------
__global__ __launch_bounds__(256)
void ln_bf16(const float* __restrict__ act, const float* __restrict__ scale,
             const float* __restrict__ bias, u16* __restrict__ X)
{
    const int row = blockIdx.x;
    const int tid = threadIdx.x;
    const float4 v = ((const float4*)(act + (size_t)row * 1024))[tid];
    float s  = v.x + v.y + v.z + v.w;
    float ss = v.x * v.x + v.y * v.y + v.z * v.z + v.w * v.w;
#pragma unroll
    for (int off = 32; off > 0; off >>= 1) {
        s  += __shfl_xor(s, off, 64);
        ss += __shfl_xor(ss, off, 64);
    }
    __shared__ float red[8];
    const int wave = tid >> 6, lane = tid & 63;
    if (lane == 0) { red[wave] = s; red[4 + wave] = ss; }
    __syncthreads();
    s  = red[0] + red[1] + red[2] + red[3];
    ss = red[4] + red[5] + red[6] + red[7];
    const float mu  = s * (1.0f / 1024.0f);
    const float var = ss * (1.0f / 1024.0f) - mu * mu;
    const float rs  = rsqrtf(var + 1e-5f);
    const float4 sc = ((const float4*)scale)[tid];
    const float4 bi = ((const float4*)bias)[tid];
    ushort4 o;
    o.x = f2bf((v.x - mu) * rs * sc.x + bi.x);
    o.y = f2bf((v.y - mu) * rs * sc.y + bi.y);
    o.z = f2bf((v.z - mu) * rs * sc.z + bi.z);
    o.w = f2bf((v.w - mu) * rs * sc.w + bi.w);
    ((ushort4*)(X + (size_t)row * 1024))[tid] = o;
}

// ---------------------------------------------------------------------------
// bf16 GEMM, m97 structure: C[M][N] = A[M][K] * Bt[N][K]^T + bias (+ReLU)
// 128x128 block tile, BK=32, 4 waves (2x2), each wave 4x4 MFMA 16x16x32 tiles.
// global_load_lds width-16 staging (LDS layout contiguous, no padding).
// M,N multiples of 128; K multiple of 32.
// ---------------------------------------------------------------------------
template <bool BF16_OUT, bool RELU>
__global__ __launch_bounds__(256)
void gemm_bt(const u16* __restrict__ A,    // [M][K] bf16 bits
             const u16* __restrict__ Bt,   // [N][K] bf16 bits
             const float* __restrict__ bias, // [N]
             void* __restrict__ Cout,
             int M, int N, int K)
{
    __shared__ __align__(16) u16 Alds[128 * 32];
    __shared__ __align__(16) u16 Blds[128 * 32];

    const int tid  = threadIdx.x;
    const int wave = tid >> 6;
    const int lane = tid & 63;
    const int wm   = wave & 1;    // wave position in M (2 waves)
    const int wn   = wave >> 1;   // wave position in N (2 waves)
    const int quad = lane >> 4;
    const int l16  = lane & 15;

    const int bm = blockIdx.x;
    const int bn = blockIdx.y;

    const u16* Ag = A  + (size_t)bm * 128 * K;
    const u16* Bg = Bt + (size_t)bn * 128 * K;

    // staging addressing: per issue, wave writes 1 KiB (16 rows x 64 B) to LDS
    const int srow = lane >> 2;        // row within 16-row chunk
    const int scol = (lane & 3) * 8;   // k-element offset (8 bf16 = 16 B)

    floatx4 acc[4][4];
#pragma unroll
    for (int i = 0; i < 4; ++i)
#pragma unroll
        for (int j = 0; j < 4; ++j)
            acc[i][j] = (floatx4){0.f, 0.f, 0.f, 0.f};

    for (int k0 = 0; k0 < K; k0 += 32) {
        __syncthreads();   // previous iteration's LDS reads done
#pragma unroll
        for (int r = 0; r < 2; ++r) {
            const int chunk = wave * 2 + r;        // 8 chunks x 16 rows = 128
            const int row = chunk * 16 + srow;
            __builtin_amdgcn_global_load_lds(
                (AS1 void*)(Ag + (size_t)row * K + k0 + scol),
                (AS3 void*)(&Alds[chunk * 16 * 32]), 16, 0, 0);
            __builtin_amdgcn_global_load_lds(
                (AS1 void*)(Bg + (size_t)row * K + k0 + scol),
                (AS3 void*)(&Blds[chunk * 16 * 32]), 16, 0, 0);
        }
        __syncthreads();   // staging drained (compiler emits vmcnt(0) before barrier)

        bf16x8 af[4], bfr[4];
#pragma unroll
        for (int mi = 0; mi < 4; ++mi) {
            const int arow = wm * 64 + mi * 16 + l16;
            af[mi] = *(const bf16x8*)(&Alds[arow * 32 + quad * 8]);
        }
#pragma unroll
        for (int ni = 0; ni < 4; ++ni) {
            const int brow = wn * 64 + ni * 16 + l16;
            bfr[ni] = *(const bf16x8*)(&Blds[brow * 32 + quad * 8]);
        }
#pragma unroll
        for (int mi = 0; mi < 4; ++mi)
#pragma unroll
            for (int ni = 0; ni < 4; ++ni)
                acc[mi][ni] = __builtin_amdgcn_mfma_f32_16x16x32_bf16(
                    af[mi], bfr[ni], acc[mi][ni], 0, 0, 0);
    }

    // epilogue: C/D layout col = lane&15, row = quad*4 + reg  [verified m89/m91]
    const int mbase = bm * 128 + wm * 64;
    const int nbase = bn * 128 + wn * 64;
#pragma unroll
    for (int ni = 0; ni < 4; ++ni) {
        const int col = nbase + ni * 16 + l16;
        const float bv = bias[col];
#pragma unroll
        for (int mi = 0; mi < 4; ++mi) {
#pragma unroll
            for (int r = 0; r < 4; ++r) {
                const int row = mbase + mi * 16 + quad * 4 + r;
                float v = acc[mi][ni][r] + bv;
                if (RELU) v = fmaxf(v, 0.f);
                if (BF16_OUT)
                    ((u16*)Cout)[(size_t)row * N + col] = f2bf(v);
                else
                    ((float*)Cout)[(size_t)row * N + col] = v;
            }
        }
    }
}

// ---------------------------------------------------------------------------
// inputs: 0 act(4,2048,1024) f32, 1 mask(unused), 2 ln_scale(1024),
//         3 ln_bias(1024), 4 w1(1024,4096), 5 b1(4096), 6 w2(4096,1024),
//         7 b2(1024). out: (4,2048,1024) f32.
// ws layout (bf16 bits): X[8192*1024] | W1t[4096*1024] | W2t[1024*4096] |
//                        H[8192*4096]  -> 100,663,296 bytes total
// ---------------------------------------------------------------------------
extern "C" void kernel_launch(void* const* d_in, const int* in_sizes, int n_in,
                              void* d_out, int out_size, void* d_ws, size_t ws_size,
                              hipStream_t stream)
{
    const float* act      = (const float*)d_in[0];
    const float* ln_scale = (const float*)d_in[2];
    const float* ln_bias  = (const float*)d_in[3];
    const float* w1       = (const float*)d_in[4];
    const float* b1       = (const float*)d_in[5];
    const float* w2       = (const float*)d_in[6];
    const float* b2       = (const float*)d_in[7];
    float* out = (float*)d_out;

    const int M = 8192, C = 1024, CI = 4096;

    u16* X   = (u16*)d_ws;                 // [M][C]
    u16* W1t = X   + (size_t)M * C;        // [CI][C]
    u16* W2t = W1t + (size_t)CI * C;       // [C][CI]
    u16* H   = W2t + (size_t)C * CI;       // [M][CI]

    // weights -> bf16, transposed to [N][K]
    transpose_cvt<<<dim3(CI / 32, C / 32), dim3(32, 8), 0, stream>>>(w1, W1t, C, CI);
    transpose_cvt<<<dim3(C / 32, CI / 32), dim3(32, 8), 0, stream>>>(w2, W2t, CI, C);
    // fused layernorm -> bf16
    ln_bf16<<<M, 256, 0, stream>>>(act, ln_scale, ln_bias, X);
    // H = relu(X @ W1 + b1), bf16
    gemm_bt<true, true><<<dim3(M / 128, CI / 128), 256, 0, stream>>>(
        X, W1t, b1, (void*)H, M, CI, C);
    // out = H @ W2 + b2, fp32
    gemm_bt<false, false><<<dim3(M / 128, C / 128), 256, 0, stream>>>(
        H, W2t, b2, (void*)out, M, C, CI);
}

// Round 2
// 285.969 us; speedup vs baseline: 1.0682x; 1.0682x over previous
//
#include <hip/hip_runtime.h>
#include <hip/hip_bf16.h>
#include <cstdint>

typedef unsigned short u16;
typedef __bf16 bf16x8 __attribute__((ext_vector_type(8)));
typedef float floatx4 __attribute__((ext_vector_type(4)));

#define AS1 __attribute__((address_space(1)))
#define AS3 __attribute__((address_space(3)))

// round-to-nearest-even f32 -> bf16 bits (inputs are finite; NaN path not needed)
static __device__ __forceinline__ u16 f2bf(float f) {
    union { float f; unsigned int u; } v; v.f = f;
    unsigned int u = v.u;
    return (u16)((u + 0x7FFFu + ((u >> 16) & 1u)) >> 16);
}

// ---------------------------------------------------------------------------
// Transpose + fp32->bf16 convert: in[R][Ccols] fp32 -> out[Ccols][R] bf16 bits
// R, Ccols multiples of 32. block (32,8), grid (Ccols/32, R/32).
// ---------------------------------------------------------------------------
__global__ __launch_bounds__(256)
void transpose_cvt(const float* __restrict__ in, u16* __restrict__ out,
                   int R, int Ccols)
{
    __shared__ float tile[32][33];
    const int tx = threadIdx.x;   // 0..31
    const int ty = threadIdx.y;   // 0..7
    const int c0 = blockIdx.x * 32;
    const int r0 = blockIdx.y * 32;
#pragma unroll
    for (int i = 0; i < 32; i += 8)
        tile[ty + i][tx] = in[(size_t)(r0 + ty + i) * Ccols + (c0 + tx)];
    __syncthreads();
#pragma unroll
    for (int i = 0; i < 32; i += 8)
        out[(size_t)(c0 + ty + i) * R + (r0 + tx)] = f2bf(tile[tx][ty + i]);
}

// ---------------------------------------------------------------------------
// LayerNorm over last dim (1024) -> bf16. One block (256 thr) per row.
// ---------------------------------------------------------------------------
__global__ __launch_bounds__(256)
void ln_bf16(const float* __restrict__ act, const float* __restrict__ scale,
             const float* __restrict__ bias, u16* __restrict__ X)
{
    const int row = blockIdx.x;
    const int tid = threadIdx.x;
    const float4 v = ((const float4*)(act + (size_t)row * 1024))[tid];
    float s  = v.x + v.y + v.z + v.w;
    float ss = v.x * v.x + v.y * v.y + v.z * v.z + v.w * v.w;
#pragma unroll
    for (int off = 32; off > 0; off >>= 1) {
        s  += __shfl_xor(s, off, 64);
        ss += __shfl_xor(ss, off, 64);
    }
    __shared__ float red[8];
    const int wave = tid >> 6, lane = tid & 63;
    if (lane == 0) { red[wave] = s; red[4 + wave] = ss; }
    __syncthreads();
    s  = red[0] + red[1] + red[2] + red[3];
    ss = red[4] + red[5] + red[6] + red[7];
    const float mu  = s * (1.0f / 1024.0f);
    const float var = ss * (1.0f / 1024.0f) - mu * mu;
    const float rs  = rsqrtf(var + 1e-5f);
    const float4 sc = ((const float4*)scale)[tid];
    const float4 bi = ((const float4*)bias)[tid];
    ushort4 o;
    o.x = f2bf((v.x - mu) * rs * sc.x + bi.x);
    o.y = f2bf((v.y - mu) * rs * sc.y + bi.y);
    o.z = f2bf((v.z - mu) * rs * sc.z + bi.z);
    o.w = f2bf((v.w - mu) * rs * sc.w + bi.w);
    ((ushort4*)(X + (size_t)row * 1024))[tid] = o;
}

// ---------------------------------------------------------------------------
// bf16 GEMM: C[M][N] = A[M][K] * Bt[N][K]^T + bias (+ReLU)
// 128x128 block tile, templated BK (32 or 64), 4 waves (2x2), each wave 4x4
// MFMA 16x16x32 tiles. global_load_lds width-16 staging with XOR bank swizzle:
//   LDS slot s at row r holds global k-slot s ^ key(r)
//   key(r) = (r>>1)&3 for BK=32 (4 slots/row), r&7 for BK=64 (8 slots/row)
// -> each quad's 16 lanes spread over all 8 bank-groups 2x (2-way = free, m136)
// Read-side key reduces to a per-lane constant -> zero extra per-iter VALU.
// M,N multiples of 128; K multiple of BK.
// ---------------------------------------------------------------------------
template <int BK, bool BF16_OUT, bool RELU>
__global__ __launch_bounds__(256)
void gemm_bt(const u16* __restrict__ A,      // [M][K] bf16 bits
             const u16* __restrict__ Bt,     // [N][K] bf16 bits
             const float* __restrict__ bias, // [N]
             void* __restrict__ Cout,
             int M, int N, int K)
{
    constexpr int SLOTS  = BK / 8;      // 16B slots per LDS row (4 or 8)
    constexpr int RPI    = 64 / SLOTS;  // rows covered per 1KB wave issue (16 or 8)
    constexpr int IPW    = SLOTS / 2;   // issues per wave per matrix (2 or 4)
    constexpr int HALVES = BK / 32;     // k-halves per LDS tile (1 or 2)

    __shared__ __align__(16) u16 Alds[128 * BK];
    __shared__ __align__(16) u16 Blds[128 * BK];

    const int tid  = threadIdx.x;
    const int wave = tid >> 6;
    const int lane = tid & 63;
    const int wm   = wave & 1;    // wave position in M (2 waves)
    const int wn   = wave >> 1;   // wave position in N (2 waves)
    const int quad = lane >> 4;
    const int l16  = lane & 15;

    const int bm = blockIdx.x;
    const int bn = blockIdx.y;

    const u16* Ag = A  + (size_t)bm * 128 * K;
    const u16* Bg = Bt + (size_t)bn * 128 * K;

    // staging: lane -> (row srow, stored slot s_st = lane%SLOTS); fetch global
    // slot s_g = s_st ^ key(srow) so that read-time slot q^key(row) is global q.
    const int srow = lane / SLOTS;
    const int s_st = lane & (SLOTS - 1);
    const int s_g  = (SLOTS == 4) ? (s_st ^ ((srow >> 1) & 3))
                                  : (s_st ^ (srow & 7));
    const int scol = s_g * 8;     // k-element offset of the fetched 16B

    // read-side swizzle key (per-lane constant; row bases are multiples of 16)
    const int rkey = (SLOTS == 4) ? ((l16 >> 1) & 3) : (l16 & 7);

    floatx4 acc[4][4];
#pragma unroll
    for (int i = 0; i < 4; ++i)
#pragma unroll
        for (int j = 0; j < 4; ++j)
            acc[i][j] = (floatx4){0.f, 0.f, 0.f, 0.f};

    for (int k0 = 0; k0 < K; k0 += BK) {
        __syncthreads();   // previous iteration's LDS reads done
#pragma unroll
        for (int r = 0; r < IPW; ++r) {
            const int chunk = wave * IPW + r;      // 1KB chunks, 8 or 16 total
            const int row = chunk * RPI + srow;
            __builtin_amdgcn_global_load_lds(
                (AS1 void*)(Ag + (size_t)row * K + k0 + scol),
                (AS3 void*)(&Alds[chunk * 512]), 16, 0, 0);
            __builtin_amdgcn_global_load_lds(
                (AS1 void*)(Bg + (size_t)row * K + k0 + scol),
                (AS3 void*)(&Blds[chunk * 512]), 16, 0, 0);
        }
        __syncthreads();   // staging drained

#pragma unroll
        for (int h = 0; h < HALVES; ++h) {
            const int slot = ((quad + 4 * h) ^ rkey) * 8;  // u16 offset in row
            bf16x8 af[4], bfr[4];
#pragma unroll
            for (int mi = 0; mi < 4; ++mi) {
                const int arow = wm * 64 + mi * 16 + l16;
                af[mi] = *(const bf16x8*)(&Alds[arow * BK + slot]);
            }
#pragma unroll
            for (int ni = 0; ni < 4; ++ni) {
                const int brow = wn * 64 + ni * 16 + l16;
                bfr[ni] = *(const bf16x8*)(&Blds[brow * BK + slot]);
            }
#pragma unroll
            for (int mi = 0; mi < 4; ++mi)
#pragma unroll
                for (int ni = 0; ni < 4; ++ni)
                    acc[mi][ni] = __builtin_amdgcn_mfma_f32_16x16x32_bf16(
                        af[mi], bfr[ni], acc[mi][ni], 0, 0, 0);
        }
    }

    // epilogue: C/D layout col = lane&15, row = quad*4 + reg  [verified m89/m91]
    const int mbase = bm * 128 + wm * 64;
    const int nbase = bn * 128 + wn * 64;
#pragma unroll
    for (int ni = 0; ni < 4; ++ni) {
        const int col = nbase + ni * 16 + l16;
        const float bv = bias[col];
#pragma unroll
        for (int mi = 0; mi < 4; ++mi) {
#pragma unroll
            for (int r = 0; r < 4; ++r) {
                const int row = mbase + mi * 16 + quad * 4 + r;
                float v = acc[mi][ni][r] + bv;
                if (RELU) v = fmaxf(v, 0.f);
                if (BF16_OUT)
                    ((u16*)Cout)[(size_t)row * N + col] = f2bf(v);
                else
                    ((float*)Cout)[(size_t)row * N + col] = v;
            }
        }
    }
}

// ---------------------------------------------------------------------------
// inputs: 0 act(4,2048,1024) f32, 1 mask(unused), 2 ln_scale(1024),
//         3 ln_bias(1024), 4 w1(1024,4096), 5 b1(4096), 6 w2(4096,1024),
//         7 b2(1024). out: (4,2048,1024) f32.
// ws layout (bf16 bits): X[8192*1024] | W1t[4096*1024] | W2t[1024*4096] |
//                        H[8192*4096]  -> 100,663,296 bytes total
// ---------------------------------------------------------------------------
extern "C" void kernel_launch(void* const* d_in, const int* in_sizes, int n_in,
                              void* d_out, int out_size, void* d_ws, size_t ws_size,
                              hipStream_t stream)
{
    const float* act      = (const float*)d_in[0];
    const float* ln_scale = (const float*)d_in[2];
    const float* ln_bias  = (const float*)d_in[3];
    const float* w1       = (const float*)d_in[4];
    const float* b1       = (const float*)d_in[5];
    const float* w2       = (const float*)d_in[6];
    const float* b2       = (const float*)d_in[7];
    float* out = (float*)d_out;

    const int M = 8192, C = 1024, CI = 4096;

    u16* X   = (u16*)d_ws;                 // [M][C]
    u16* W1t = X   + (size_t)M * C;        // [CI][C]
    u16* W2t = W1t + (size_t)CI * C;       // [C][CI]
    u16* H   = W2t + (size_t)C * CI;       // [M][CI]

    // weights -> bf16, transposed to [N][K]
    transpose_cvt<<<dim3(CI / 32, C / 32), dim3(32, 8), 0, stream>>>(w1, W1t, C, CI);
    transpose_cvt<<<dim3(C / 32, CI / 32), dim3(32, 8), 0, stream>>>(w2, W2t, CI, C);
    // fused layernorm -> bf16
    ln_bf16<<<M, 256, 0, stream>>>(act, ln_scale, ln_bias, X);
    // H = relu(X @ W1 + b1), bf16.  2048 blocks -> residency-limited, BK=32.
    gemm_bt<32, true, true><<<dim3(M / 128, CI / 128), 256, 0, stream>>>(
        X, W1t, b1, (void*)H, M, CI, C);
    // out = H @ W2 + b2, fp32.  512 blocks = 2/CU (grid-limited) -> BK=64:
    // half the barriers, 32KB LDS is free here.
    gemm_bt<64, false, false><<<dim3(M / 128, C / 128), 256, 0, stream>>>(
        H, W2t, b2, (void*)out, M, C, CI);
}

// Round 3
// 279.278 us; speedup vs baseline: 1.0938x; 1.0240x over previous
//
#include <hip/hip_runtime.h>
#include <hip/hip_bf16.h>
#include <cstdint>

typedef unsigned short u16;
typedef __bf16 bf16x8 __attribute__((ext_vector_type(8)));
typedef float floatx4 __attribute__((ext_vector_type(4)));

#define AS1 __attribute__((address_space(1)))
#define AS3 __attribute__((address_space(3)))

// round-to-nearest-even f32 -> bf16 bits (inputs are finite; NaN path not needed)
static __device__ __forceinline__ u16 f2bf(float f) {
    union { float f; unsigned int u; } v; v.f = f;
    unsigned int u = v.u;
    return (u16)((u + 0x7FFFu + ((u >> 16) & 1u)) >> 16);
}

// ---------------------------------------------------------------------------
// Transpose + fp32->bf16 convert: in[R][Ccols] fp32 -> out[Ccols][R] bf16 bits
// R, Ccols multiples of 32. block (32,8), grid (Ccols/32, R/32).
// ---------------------------------------------------------------------------
__global__ __launch_bounds__(256)
void transpose_cvt(const float* __restrict__ in, u16* __restrict__ out,
                   int R, int Ccols)
{
    __shared__ float tile[32][33];
    const int tx = threadIdx.x;   // 0..31
    const int ty = threadIdx.y;   // 0..7
    const int c0 = blockIdx.x * 32;
    const int r0 = blockIdx.y * 32;
#pragma unroll
    for (int i = 0; i < 32; i += 8)
        tile[ty + i][tx] = in[(size_t)(r0 + ty + i) * Ccols + (c0 + tx)];
    __syncthreads();
#pragma unroll
    for (int i = 0; i < 32; i += 8)
        out[(size_t)(c0 + ty + i) * R + (r0 + tx)] = f2bf(tile[tx][ty + i]);
}

// ---------------------------------------------------------------------------
// LayerNorm over last dim (1024) -> bf16. One block (256 thr) per row.
// ---------------------------------------------------------------------------
__global__ __launch_bounds__(256)
void ln_bf16(const float* __restrict__ act, const float* __restrict__ scale,
             const float* __restrict__ bias, u16* __restrict__ X)
{
    const int row = blockIdx.x;
    const int tid = threadIdx.x;
    const float4 v = ((const float4*)(act + (size_t)row * 1024))[tid];
    float s  = v.x + v.y + v.z + v.w;
    float ss = v.x * v.x + v.y * v.y + v.z * v.z + v.w * v.w;
#pragma unroll
    for (int off = 32; off > 0; off >>= 1) {
        s  += __shfl_xor(s, off, 64);
        ss += __shfl_xor(ss, off, 64);
    }
    __shared__ float red[8];
    const int wave = tid >> 6, lane = tid & 63;
    if (lane == 0) { red[wave] = s; red[4 + wave] = ss; }
    __syncthreads();
    s  = red[0] + red[1] + red[2] + red[3];
    ss = red[4] + red[5] + red[6] + red[7];
    const float mu  = s * (1.0f / 1024.0f);
    const float var = ss * (1.0f / 1024.0f) - mu * mu;
    const float rs  = rsqrtf(var + 1e-5f);
    const float4 sc = ((const float4*)scale)[tid];
    const float4 bi = ((const float4*)bias)[tid];
    ushort4 o;
    o.x = f2bf((v.x - mu) * rs * sc.x + bi.x);
    o.y = f2bf((v.y - mu) * rs * sc.y + bi.y);
    o.z = f2bf((v.z - mu) * rs * sc.z + bi.z);
    o.w = f2bf((v.w - mu) * rs * sc.w + bi.w);
    ((ushort4*)(X + (size_t)row * 1024))[tid] = o;
}

// ---------------------------------------------------------------------------
// bf16 GEMM: C[M][N] = A[M][K] * Bt[N][K]^T + bias (+ReLU)
// 128x128 block tile, templated BK, 4 waves (2x2), each wave 4x4 MFMA
// 16x16x32 tiles. global_load_lds width-16 staging + XOR bank swizzle
// (R2: conflicts 8.39M -> 0, verified).
//
// OPERAND-SWAPPED MFMA: mfma(bfr, af, acc) -> D[i=n][j=m] with
//   m = l16, n = quad*4 + reg  (per lane: 4 CONSECUTIVE columns of C)
// so the epilogue stores ushort4/float4 contiguously (4x fewer stores,
// full-line write-combining) and bias is one float4 load per ni.
// M,N multiples of 128; K multiple of BK.
// ---------------------------------------------------------------------------
template <int BK, bool BF16_OUT, bool RELU>
__global__ __launch_bounds__(256)
void gemm_bt(const u16* __restrict__ A,      // [M][K] bf16 bits
             const u16* __restrict__ Bt,     // [N][K] bf16 bits
             const float* __restrict__ bias, // [N]
             void* __restrict__ Cout,
             int M, int N, int K)
{
    constexpr int SLOTS  = BK / 8;      // 16B slots per LDS row (4 or 8)
    constexpr int RPI    = 64 / SLOTS;  // rows covered per 1KB wave issue
    constexpr int IPW    = SLOTS / 2;   // issues per wave per matrix
    constexpr int HALVES = BK / 32;     // k-halves per LDS tile

    __shared__ __align__(16) u16 Alds[128 * BK];
    __shared__ __align__(16) u16 Blds[128 * BK];

    const int tid  = threadIdx.x;
    const int wave = tid >> 6;
    const int lane = tid & 63;
    const int wm   = wave & 1;    // wave position in M (2 waves)
    const int wn   = wave >> 1;   // wave position in N (2 waves)
    const int quad = lane >> 4;
    const int l16  = lane & 15;

    const int bm = blockIdx.x;
    const int bn = blockIdx.y;

    const u16* Ag = A  + (size_t)bm * 128 * K;
    const u16* Bg = Bt + (size_t)bn * 128 * K;

    // staging: lane -> (row srow, stored slot s_st); fetch global slot
    // s_g = s_st ^ key(srow) so read-time slot q^key(row) yields global q.
    const int srow = lane / SLOTS;
    const int s_st = lane & (SLOTS - 1);
    const int s_g  = (SLOTS == 4) ? (s_st ^ ((srow >> 1) & 3))
                                  : (s_st ^ (srow & 7));
    const int scol = s_g * 8;     // k-element offset of the fetched 16B

    // read-side swizzle key (per-lane constant)
    const int rkey = (SLOTS == 4) ? ((l16 >> 1) & 3) : (l16 & 7);

    floatx4 acc[4][4];
#pragma unroll
    for (int i = 0; i < 4; ++i)
#pragma unroll
        for (int j = 0; j < 4; ++j)
            acc[i][j] = (floatx4){0.f, 0.f, 0.f, 0.f};

    for (int k0 = 0; k0 < K; k0 += BK) {
        __syncthreads();   // previous iteration's LDS reads done
#pragma unroll
        for (int r = 0; r < IPW; ++r) {
            const int chunk = wave * IPW + r;      // 1KB chunks
            const int row = chunk * RPI + srow;
            __builtin_amdgcn_global_load_lds(
                (AS1 void*)(Ag + (size_t)row * K + k0 + scol),
                (AS3 void*)(&Alds[chunk * 512]), 16, 0, 0);
            __builtin_amdgcn_global_load_lds(
                (AS1 void*)(Bg + (size_t)row * K + k0 + scol),
                (AS3 void*)(&Blds[chunk * 512]), 16, 0, 0);
        }
        __syncthreads();   // staging drained

#pragma unroll
        for (int h = 0; h < HALVES; ++h) {
            const int slot = ((quad + 4 * h) ^ rkey) * 8;  // u16 offset in row
            bf16x8 af[4], bfr[4];
#pragma unroll
            for (int mi = 0; mi < 4; ++mi) {
                const int arow = wm * 64 + mi * 16 + l16;
                af[mi] = *(const bf16x8*)(&Alds[arow * BK + slot]);
            }
#pragma unroll
            for (int ni = 0; ni < 4; ++ni) {
                const int brow = wn * 64 + ni * 16 + l16;
                bfr[ni] = *(const bf16x8*)(&Blds[brow * BK + slot]);
            }
            // swapped operands: D[i=n (quad*4+reg)][j=m (l16)]
#pragma unroll
            for (int mi = 0; mi < 4; ++mi)
#pragma unroll
                for (int ni = 0; ni < 4; ++ni)
                    acc[mi][ni] = __builtin_amdgcn_mfma_f32_16x16x32_bf16(
                        bfr[ni], af[mi], acc[mi][ni], 0, 0, 0);
        }
    }

    // epilogue: lane (l16, quad) of acc[mi][ni] holds
    //   C[m = mbase+mi*16+l16][n = nbase+ni*16+quad*4 + r], r=0..3 contiguous
    const int mbase = bm * 128 + wm * 64;
    const int nbase = bn * 128 + wn * 64;
#pragma unroll
    for (int mi = 0; mi < 4; ++mi) {
        const int m = mbase + mi * 16 + l16;
#pragma unroll
        for (int ni = 0; ni < 4; ++ni) {
            const int n0 = nbase + ni * 16 + quad * 4;
            const float4 bv = *(const float4*)&bias[n0];
            float v0 = acc[mi][ni][0] + bv.x;
            float v1 = acc[mi][ni][1] + bv.y;
            float v2 = acc[mi][ni][2] + bv.z;
            float v3 = acc[mi][ni][3] + bv.w;
            if (RELU) {
                v0 = fmaxf(v0, 0.f); v1 = fmaxf(v1, 0.f);
                v2 = fmaxf(v2, 0.f); v3 = fmaxf(v3, 0.f);
            }
            if (BF16_OUT) {
                ushort4 o = { f2bf(v0), f2bf(v1), f2bf(v2), f2bf(v3) };
                *(ushort4*)&((u16*)Cout)[(size_t)m * N + n0] = o;
            } else {
                float4 o = { v0, v1, v2, v3 };
                *(float4*)&((float*)Cout)[(size_t)m * N + n0] = o;
            }
        }
    }
}

// ---------------------------------------------------------------------------
// inputs: 0 act(4,2048,1024) f32, 1 mask(unused), 2 ln_scale(1024),
//         3 ln_bias(1024), 4 w1(1024,4096), 5 b1(4096), 6 w2(4096,1024),
//         7 b2(1024). out: (4,2048,1024) f32.
// ws layout (bf16 bits): X[8192*1024] | W1t[4096*1024] | W2t[1024*4096] |
//                        H[8192*4096]  -> 100,663,296 bytes total
// ---------------------------------------------------------------------------
extern "C" void kernel_launch(void* const* d_in, const int* in_sizes, int n_in,
                              void* d_out, int out_size, void* d_ws, size_t ws_size,
                              hipStream_t stream)
{
    const float* act      = (const float*)d_in[0];
    const float* ln_scale = (const float*)d_in[2];
    const float* ln_bias  = (const float*)d_in[3];
    const float* w1       = (const float*)d_in[4];
    const float* b1       = (const float*)d_in[5];
    const float* w2       = (const float*)d_in[6];
    const float* b2       = (const float*)d_in[7];
    float* out = (float*)d_out;

    const int M = 8192, C = 1024, CI = 4096;

    u16* X   = (u16*)d_ws;                 // [M][C]
    u16* W1t = X   + (size_t)M * C;        // [CI][C]
    u16* W2t = W1t + (size_t)CI * C;       // [C][CI]
    u16* H   = W2t + (size_t)C * CI;       // [M][CI]

    // weights -> bf16, transposed to [N][K]
    transpose_cvt<<<dim3(CI / 32, C / 32), dim3(32, 8), 0, stream>>>(w1, W1t, C, CI);
    transpose_cvt<<<dim3(C / 32, CI / 32), dim3(32, 8), 0, stream>>>(w2, W2t, CI, C);
    // fused layernorm -> bf16
    ln_bf16<<<M, 256, 0, stream>>>(act, ln_scale, ln_bias, X);
    // H = relu(X @ W1 + b1), bf16.  BK=64: half the barrier drains (proved
    // -30% on GEMM2 in R2); 32KB LDS caps at 5 blocks/CU which 2048 blocks
    // tolerate fine.
    gemm_bt<64, true, true><<<dim3(M / 128, CI / 128), 256, 0, stream>>>(
        X, W1t, b1, (void*)H, M, CI, C);
    // out = H @ W2 + b2, fp32.  BK=64.
    gemm_bt<64, false, false><<<dim3(M / 128, C / 128), 256, 0, stream>>>(
        H, W2t, b2, (void*)out, M, C, CI);
}